// Round 4
// baseline (491.569 us; speedup 1.0000x reference)
//
#include <hip/hip_runtime.h>

#define L_NODES 100000
#define NFEAT   256
#define JDIM    128

typedef __bf16 bf16x8 __attribute__((ext_vector_type(8)));
typedef __bf16 bf16x4 __attribute__((ext_vector_type(4)));
typedef float  floatx4 __attribute__((ext_vector_type(4)));

// ---------------------------------------------------------------------------
// Prep: WtH[n][k] = bf16(W_h1[k][n]), WtG[n][k] = bf16(W_g1[k][n])  (64 KB each)
// ---------------------------------------------------------------------------
__global__ __launch_bounds__(256) void k_prep(
    const float* __restrict__ Wh, const float* __restrict__ Wg,
    __bf16* __restrict__ WtH, __bf16* __restrict__ WtG)
{
    int i = blockIdx.x * 256 + threadIdx.x;   // 32768
    int n = i >> 8, k = i & 255;
    WtH[i] = (__bf16)Wh[k * JDIM + n];
    WtG[i] = (__bf16)Wg[k * JDIM + n];
}

// ---------------------------------------------------------------------------
// Kernel 1 (MFMA): Hb = bf16(relu(X @ W_h1 + b))   M=L K=256 N=128
// Block = 64 rows, 4 waves; wave = 1 m-tile x 8 n-tiles. A loaded fp32
// direct global->VGPR, converted in-register to bf16 frags. No staging LDS;
// LDS only for the coalescing epilogue.
// ---------------------------------------------------------------------------
__global__ __launch_bounds__(256) void k_h1_mfma(
    const float* __restrict__ X, const __bf16* __restrict__ WtH,
    const float* __restrict__ b, __bf16* __restrict__ Hb)
{
    __shared__ __bf16 Os[64][136];

    const int tid  = threadIdx.x;
    const int row0 = blockIdx.x * 64;
    const int wave = tid >> 6, lane = tid & 63;
    const int lm = lane & 15, lq = lane >> 4;

    int arow = row0 + wave * 16 + lm;
    if (arow >= L_NODES) arow = L_NODES - 1;
    const float* xp = X + (size_t)arow * NFEAT + lq * 8;

    // hoist all A: 16 float4 loads -> 8 bf16x8 frags (one latency exposure)
    bf16x8 aall[8];
    #pragma unroll
    for (int ks = 0; ks < 8; ++ks) {
        float4 v0 = *(const float4*)(xp + ks * 32);
        float4 v1 = *(const float4*)(xp + ks * 32 + 4);
        bf16x8 a;
        a[0]=(__bf16)v0.x; a[1]=(__bf16)v0.y; a[2]=(__bf16)v0.z; a[3]=(__bf16)v0.w;
        a[4]=(__bf16)v1.x; a[5]=(__bf16)v1.y; a[6]=(__bf16)v1.z; a[7]=(__bf16)v1.w;
        aall[ks] = a;
    }
    __builtin_amdgcn_sched_barrier(0);

    const __bf16* bbase = WtH + (size_t)lm * 256 + lq * 8;
    floatx4 acc[8] = {};
    #pragma unroll
    for (int ks = 0; ks < 8; ++ks) {
        bf16x8 bc[8];
        #pragma unroll
        for (int nt = 0; nt < 8; ++nt)
            bc[nt] = *(const bf16x8*)(bbase + (size_t)nt * 16 * 256 + ks * 32);
        #pragma unroll
        for (int nt = 0; nt < 8; ++nt)
            acc[nt] = __builtin_amdgcn_mfma_f32_16x16x32_bf16(
                aall[ks], bc[nt], acc[nt], 0, 0, 0);
    }

    // D[m=lq*4+p][n=nt*16+lm] -> bias+relu -> LDS -> coalesced bf16 store
    #pragma unroll
    for (int nt = 0; nt < 8; ++nt) {
        int col = nt * 16 + lm;
        float bias = b[col];
        #pragma unroll
        for (int p = 0; p < 4; ++p)
            Os[wave * 16 + lq * 4 + p][col] = (__bf16)fmaxf(acc[nt][p] + bias, 0.f);
    }
    __syncthreads();
    #pragma unroll
    for (int it = 0; it < 4; ++it) {
        int fid = it * 256 + tid;
        int row = fid >> 4, fr = fid & 15;
        int g = row0 + row;
        if (g < L_NODES)
            *(bf16x8*)(Hb + (size_t)g * JDIM + fr * 8) = *(bf16x8*)&Os[row][fr * 8];
    }
}

// ---------------------------------------------------------------------------
// Kernel 2 (MFMA): E1b[i] = bf16(relu(mean_s relu(concat(Hb[idx0],Hb[idx1])@Wg+b)))
// Block = 16 nodes x 8 samples; wave = 2 sample-tiles x ALL 8 n-tiles
// (no intra-block gather duplication: each gathered row loaded exactly once).
// All 16 A-gather loads hoisted and PINNED above the MFMA loop via
// sched_barrier; __launch_bounds__(256,2) lets the allocator keep them live.
// ---------------------------------------------------------------------------
__global__ __launch_bounds__(256, 2) void k_fk2_mfma(
    const __bf16* __restrict__ Hb, const __bf16* __restrict__ Wt,
    const float* __restrict__ b,
    const int* __restrict__ idx0, const int* __restrict__ idx1,
    __bf16* __restrict__ E1b)
{
    __shared__ float red[4][16][132];   // 33.8 KB: per-wave partial sums

    const int tid  = threadIdx.x;
    const int i0   = blockIdx.x * 16;
    const int wave = tid >> 6, lane = tid & 63;
    const int lm = lane & 15, lq = lane >> 4;

    // wave handles samples s = wave*2 + t, t in {0,1}
    bf16x8 aall[2][8];
    #pragma unroll
    for (int t = 0; t < 2; ++t) {
        int s  = wave * 2 + t;
        int r0 = idx0[(size_t)s * L_NODES + i0 + lm];
        int r1 = idx1[(size_t)s * L_NODES + i0 + lm];
        const __bf16* p0 = Hb + (size_t)r0 * JDIM + lq * 8;
        const __bf16* p1 = Hb + (size_t)r1 * JDIM + lq * 8;
        #pragma unroll
        for (int kc = 0; kc < 4; ++kc) {
            aall[t][kc]     = *(const bf16x8*)(p0 + kc * 32);
            aall[t][kc + 4] = *(const bf16x8*)(p1 + kc * 32);
        }
    }
    __builtin_amdgcn_sched_barrier(0);

    const __bf16* bbase = Wt + (size_t)lm * 256 + lq * 8;
    floatx4 acc[2][8] = {};
    #pragma unroll
    for (int ks = 0; ks < 8; ++ks) {
        bf16x8 bc[8];
        #pragma unroll
        for (int nt = 0; nt < 8; ++nt)
            bc[nt] = *(const bf16x8*)(bbase + (size_t)nt * 16 * 256 + ks * 32);
        #pragma unroll
        for (int t = 0; t < 2; ++t)
            #pragma unroll
            for (int nt = 0; nt < 8; ++nt)
                acc[t][nt] = __builtin_amdgcn_mfma_f32_16x16x32_bf16(
                    aall[t][ks], bc[nt], acc[t][nt], 0, 0, 0);
    }

    // bias+relu per sample, sum wave's 2 samples, LDS-combine 4 waves
    #pragma unroll
    for (int nt = 0; nt < 8; ++nt) {
        int col = nt * 16 + lm;
        float bias = b[col];
        #pragma unroll
        for (int p = 0; p < 4; ++p)
            red[wave][lq * 4 + p][col] =
                fmaxf(acc[0][nt][p] + bias, 0.f) + fmaxf(acc[1][nt][p] + bias, 0.f);
    }
    __syncthreads();
    {
        int il = tid >> 4, c0 = (tid & 15) * 8;
        bf16x8 o;
        #pragma unroll
        for (int c = 0; c < 8; ++c) {
            float s = red[0][il][c0 + c] + red[1][il][c0 + c]
                    + red[2][il][c0 + c] + red[3][il][c0 + c];
            o[c] = (__bf16)fmaxf(s * 0.125f, 0.f);
        }
        *(bf16x8*)(E1b + (size_t)(i0 + il) * JDIM + c0) = o;
    }
}

// ---------------------------------------------------------------------------
// Kernel 3 (MFMA): E2 = relu(concat(Hb,E1b) @ Wg + bg);  out = E2 @ Wf + bf
// Block = 64 rows, 4 waves; wave = 1 m-tile x 8 n-tiles, bf16 A direct loads.
// ---------------------------------------------------------------------------
__global__ __launch_bounds__(256) void k_final_mfma(
    const __bf16* __restrict__ Hb, const __bf16* __restrict__ E1b,
    const __bf16* __restrict__ Wt, const float* __restrict__ bg,
    const float* __restrict__ Wf, const float* __restrict__ bf,
    float* __restrict__ out)
{
    __shared__ __bf16 E2s[64][136];

    const int tid  = threadIdx.x;
    const int row0 = blockIdx.x * 64;
    const int wave = tid >> 6, lane = tid & 63;
    const int lm = lane & 15, lq = lane >> 4;

    int arow = row0 + wave * 16 + lm;
    if (arow >= L_NODES) arow = L_NODES - 1;
    const __bf16* hp = Hb  + (size_t)arow * JDIM + lq * 8;
    const __bf16* ep = E1b + (size_t)arow * JDIM + lq * 8;

    bf16x8 aall[8];
    #pragma unroll
    for (int kc = 0; kc < 4; ++kc) {
        aall[kc]     = *(const bf16x8*)(hp + kc * 32);
        aall[kc + 4] = *(const bf16x8*)(ep + kc * 32);
    }
    __builtin_amdgcn_sched_barrier(0);

    const __bf16* bbase = Wt + (size_t)lm * 256 + lq * 8;
    floatx4 acc[8] = {};
    #pragma unroll
    for (int ks = 0; ks < 8; ++ks) {
        bf16x8 bc[8];
        #pragma unroll
        for (int nt = 0; nt < 8; ++nt)
            bc[nt] = *(const bf16x8*)(bbase + (size_t)nt * 16 * 256 + ks * 32);
        #pragma unroll
        for (int nt = 0; nt < 8; ++nt)
            acc[nt] = __builtin_amdgcn_mfma_f32_16x16x32_bf16(
                aall[ks], bc[nt], acc[nt], 0, 0, 0);
    }

    #pragma unroll
    for (int nt = 0; nt < 8; ++nt) {
        int col = nt * 16 + lm;
        float bias = bg[col];
        #pragma unroll
        for (int p = 0; p < 4; ++p)
            E2s[wave * 16 + lq * 4 + p][col] = (__bf16)fmaxf(acc[nt][p] + bias, 0.f);
    }
    __syncthreads();

    if (tid < 128) {
        int row = tid >> 1, o = tid & 1;
        int grow = row0 + row;
        if (grow < L_NODES) {
            float a = bf[o];
            #pragma unroll
            for (int j = 0; j < 16; ++j) {
                bf16x8 v = *(bf16x8*)&E2s[row][j * 8];
                #pragma unroll
                for (int c = 0; c < 8; ++c)
                    a = fmaf((float)v[c], Wf[(j * 8 + c) * 2 + o], a);
            }
            out[(size_t)grow * 2 + o] = a;
        }
    }
}

// ---------------------------------------------------------------------------
extern "C" void kernel_launch(void* const* d_in, const int* in_sizes, int n_in,
                              void* d_out, int out_size, void* d_ws, size_t ws_size,
                              hipStream_t stream) {
    const float* X    = (const float*)d_in[0];
    const float* W_h1 = (const float*)d_in[1];
    const float* b_h1 = (const float*)d_in[2];
    const float* W_g1 = (const float*)d_in[3];
    const float* b_g1 = (const float*)d_in[4];
    const float* W_f  = (const float*)d_in[5];
    const float* b_f  = (const float*)d_in[6];
    const int*   idx0 = (const int*)d_in[7];
    const int*   idx1 = (const int*)d_in[8];
    float* out = (float*)d_out;

    __bf16* Hb  = (__bf16*)d_ws;                          // L x 128 bf16 = 25.6 MB
    __bf16* E1b = Hb + (size_t)L_NODES * JDIM;            // L x 128 bf16 = 25.6 MB
    __bf16* WtH = E1b + (size_t)L_NODES * JDIM;           // 64 KB
    __bf16* WtG = WtH + 128 * 256;                        // 64 KB

    k_prep<<<128, 256, 0, stream>>>(W_h1, W_g1, WtH, WtG);
    k_h1_mfma<<<(L_NODES + 63) / 64, 256, 0, stream>>>(X, WtH, b_h1, Hb);
    k_fk2_mfma<<<L_NODES / 16, 256, 0, stream>>>(Hb, WtG, b_g1, idx0, idx1, E1b);
    k_final_mfma<<<(L_NODES + 63) / 64, 256, 0, stream>>>(Hb, E1b, WtG, b_g1, W_f, b_f, out);
}

// Round 5
// 320.140 us; speedup vs baseline: 1.5355x; 1.5355x over previous
//
#include <hip/hip_runtime.h>

#define L_NODES 100000
#define NFEAT   256
#define JDIM    128

typedef __bf16 bf16x8 __attribute__((ext_vector_type(8)));
typedef __bf16 bf16x4 __attribute__((ext_vector_type(4)));
typedef float  floatx4 __attribute__((ext_vector_type(4)));

// ---------------------------------------------------------------------------
// Prep: WtH[n][k]=bf16(W_h1[k][n]), WtGu[n][k]=bf16(W_g1[k][n]) -> into d_out
// (d_out is dead scratch until k_final rewrites every element at the end).
// ---------------------------------------------------------------------------
__global__ __launch_bounds__(256) void k_prep(
    const float* __restrict__ Wh, const float* __restrict__ Wg,
    __bf16* __restrict__ WtH, __bf16* __restrict__ WtGu)
{
    int i = blockIdx.x * 256 + threadIdx.x;   // 32768
    int n = i >> 8, k = i & 255;
    WtH[i]  = (__bf16)Wh[k * JDIM + n];
    WtGu[i] = (__bf16)Wg[k * JDIM + n];
}

// Prep2 (runs after k_gather, when U is dead): WtGf = bf16(Wg^T) into U space
__global__ __launch_bounds__(256) void k_prep2(
    const float* __restrict__ Wg, __bf16* __restrict__ WtGf)
{
    int i = blockIdx.x * 256 + threadIdx.x;
    int n = i >> 8, k = i & 255;
    WtGf[i] = (__bf16)Wg[k * JDIM + n];
}

// ---------------------------------------------------------------------------
// Kernel 1 (MFMA): Hb = bf16(relu(X @ W_h1 + b))   [R3-proven version]
// Block 128x128, 4 waves = (mh, wc), wave = 4 m-tiles x 4 n-tiles.
// A staged fp32->bf16 through LDS in two K-halves.
// ---------------------------------------------------------------------------
__global__ __launch_bounds__(256) void k_h1_mfma(
    const float* __restrict__ X, const __bf16* __restrict__ WtH,
    const float* __restrict__ b, __bf16* __restrict__ Hb)
{
    __shared__ __bf16 As[128][136];

    const int tid  = threadIdx.x;
    const int row0 = blockIdx.x * 128;
    const int wave = tid >> 6, lane = tid & 63;
    const int mh = wave >> 1, wc = wave & 1;
    const int lm = lane & 15, lq = lane >> 4;

    const __bf16* bptr[4];
    #pragma unroll
    for (int nt = 0; nt < 4; ++nt)
        bptr[nt] = WtH + (size_t)(wc * 64 + nt * 16 + lm) * 256 + lq * 8;

    floatx4 acc[4][4] = {};
    bf16x8 bc[4], bn[4];
    #pragma unroll
    for (int nt = 0; nt < 4; ++nt) bc[nt] = *(const bf16x8*)bptr[nt];

    for (int half = 0; half < 2; ++half) {
        #pragma unroll
        for (int it = 0; it < 16; ++it) {
            int f4  = it * 256 + tid;
            int row = f4 >> 5;
            int c4  = f4 & 31;
            int grow = row0 + row; if (grow >= L_NODES) grow = L_NODES - 1;
            float4 v = *(const float4*)(X + (size_t)grow * NFEAT + half * 128 + c4 * 4);
            bf16x4 o; o[0]=(__bf16)v.x; o[1]=(__bf16)v.y; o[2]=(__bf16)v.z; o[3]=(__bf16)v.w;
            *(bf16x4*)&As[row][c4 * 4] = o;
        }
        __syncthreads();
        #pragma unroll
        for (int ksl = 0; ksl < 4; ++ksl) {
            int ks = half * 4 + ksl;
            if (ks < 7)
                #pragma unroll
                for (int nt = 0; nt < 4; ++nt)
                    bn[nt] = *(const bf16x8*)(bptr[nt] + (ks + 1) * 32);
            bf16x8 af[4];
            #pragma unroll
            for (int t = 0; t < 4; ++t)
                af[t] = *(const bf16x8*)&As[mh * 64 + t * 16 + lm][ksl * 32 + lq * 8];
            #pragma unroll
            for (int t = 0; t < 4; ++t)
                #pragma unroll
                for (int nt = 0; nt < 4; ++nt)
                    acc[t][nt] = __builtin_amdgcn_mfma_f32_16x16x32_bf16(
                        af[t], bc[nt], acc[t][nt], 0, 0, 0);
            #pragma unroll
            for (int nt = 0; nt < 4; ++nt) bc[nt] = bn[nt];
        }
        __syncthreads();
    }

    #pragma unroll
    for (int nt = 0; nt < 4; ++nt) {
        int col = wc * 64 + nt * 16 + lm;
        float bias = b[col];
        #pragma unroll
        for (int t = 0; t < 4; ++t)
            #pragma unroll
            for (int p = 0; p < 4; ++p)
                As[mh * 64 + t * 16 + lq * 4 + p][col] =
                    (__bf16)fmaxf(acc[t][nt][p] + bias, 0.f);
    }
    __syncthreads();
    {
        int row = tid >> 1, hf = tid & 1;
        int grow = row0 + row;
        if (grow < L_NODES) {
            #pragma unroll
            for (int j = 0; j < 8; ++j) {
                bf16x8 v = *(bf16x8*)&As[row][hf * 64 + j * 8];
                *(bf16x8*)(Hb + (size_t)grow * JDIM + hf * 64 + j * 8) = v;
            }
        }
    }
}

// ---------------------------------------------------------------------------
// Kernel 2a (MFMA): U = Hb @ Wg[0:128,:], V = Hb @ Wg[128:256,:]  (bf16 out)
// M=L, K=128, N=256 (U||V). Block 64 rows x 256 cols; wave (wm,wn) = 2 m-tiles
// x 8 n-tiles; wn selects U vs V. B read from WtGu: k index = wn*128 + k.
// ---------------------------------------------------------------------------
__global__ __launch_bounds__(256) void k_uv(
    const __bf16* __restrict__ Hb, const __bf16* __restrict__ WtGu,
    __bf16* __restrict__ U, __bf16* __restrict__ V)
{
    __shared__ __bf16 Os[64][264];

    const int tid  = threadIdx.x;
    const int row0 = blockIdx.x * 64;
    const int wave = tid >> 6, lane = tid & 63;
    const int wm = wave >> 1, wn = wave & 1;
    const int lm = lane & 15, lq = lane >> 4;

    bf16x8 aall[2][4];
    #pragma unroll
    for (int t = 0; t < 2; ++t) {
        int grow = row0 + wm * 32 + t * 16 + lm;
        if (grow >= L_NODES) grow = L_NODES - 1;
        const __bf16* hp = Hb + (size_t)grow * JDIM + lq * 8;
        #pragma unroll
        for (int ks = 0; ks < 4; ++ks)
            aall[t][ks] = *(const bf16x8*)(hp + ks * 32);
    }

    // B: WtGu[n][wn*128 + k]
    const __bf16* bbase = WtGu + (size_t)lm * 256 + wn * 128 + lq * 8;
    floatx4 acc[2][8] = {};
    #pragma unroll
    for (int ks = 0; ks < 4; ++ks) {
        bf16x8 bc[8];
        #pragma unroll
        for (int nt = 0; nt < 8; ++nt)
            bc[nt] = *(const bf16x8*)(bbase + (size_t)nt * 16 * 256 + ks * 32);
        #pragma unroll
        for (int t = 0; t < 2; ++t)
            #pragma unroll
            for (int nt = 0; nt < 8; ++nt)
                acc[t][nt] = __builtin_amdgcn_mfma_f32_16x16x32_bf16(
                    aall[t][ks], bc[nt], acc[t][nt], 0, 0, 0);
    }

    // D[row=wm*32+t*16+lq*4+p][col=wn*128+nt*16+lm] -> LDS -> coalesced store
    #pragma unroll
    for (int nt = 0; nt < 8; ++nt) {
        int col = wn * 128 + nt * 16 + lm;
        #pragma unroll
        for (int t = 0; t < 2; ++t)
            #pragma unroll
            for (int p = 0; p < 4; ++p)
                Os[wm * 32 + t * 16 + lq * 4 + p][col] = (__bf16)acc[t][nt][p];
    }
    __syncthreads();
    #pragma unroll
    for (int it = 0; it < 8; ++it) {
        int fid = it * 256 + tid;
        int row = fid >> 5, c8 = fid & 31;
        int grow = row0 + row;
        if (grow < L_NODES) {
            int col = c8 * 8;
            bf16x8 v = *(bf16x8*)&Os[row][col];
            if (col < 128)
                *(bf16x8*)(U + (size_t)grow * JDIM + col) = v;
            else
                *(bf16x8*)(V + (size_t)grow * JDIM + (col - 128)) = v;
        }
    }
}

// ---------------------------------------------------------------------------
// Kernel 2b (gather-add, no MFMA):
// E1b[i] = bf16(relu( (1/8) * sum_s relu(U[idx0[s,i]] + V[idx1[s,i]] + b) ))
// Block = 16 nodes; wave = 4 nodes x 16 col-chunks (256 B/row fully coalesced).
// All 16 gather loads per wave independent -> deep MLP; tiny LDS/VGPR -> high
// occupancy. This is the latency-tolerant replacement for the gather GEMM.
// ---------------------------------------------------------------------------
__global__ __launch_bounds__(256) void k_gather(
    const __bf16* __restrict__ U, const __bf16* __restrict__ V,
    const float* __restrict__ b,
    const int* __restrict__ idx0, const int* __restrict__ idx1,
    __bf16* __restrict__ E1b)
{
    __shared__ int s0[8][16], s1[8][16];

    const int tid = threadIdx.x;
    const int i0  = blockIdx.x * 16;

    if (tid < 128) {
        int s = tid >> 4, il = tid & 15;
        s0[s][il] = idx0[(size_t)s * L_NODES + i0 + il];
    } else {
        int t = tid - 128, s = t >> 4, il = t & 15;
        s1[s][il] = idx1[(size_t)s * L_NODES + i0 + il];
    }
    __syncthreads();

    const int il = tid >> 4;            // node within block
    const int c0 = (tid & 15) * 8;      // column chunk

    float bias[8];
    *(float4*)&bias[0] = *(const float4*)(b + c0);
    *(float4*)&bias[4] = *(const float4*)(b + c0 + 4);

    float acc[8] = {};
    #pragma unroll
    for (int s = 0; s < 8; ++s) {
        int r0 = s0[s][il], r1 = s1[s][il];
        bf16x8 u = *(const bf16x8*)(U + (size_t)r0 * JDIM + c0);
        bf16x8 v = *(const bf16x8*)(V + (size_t)r1 * JDIM + c0);
        #pragma unroll
        for (int p = 0; p < 8; ++p)
            acc[p] += fmaxf((float)u[p] + (float)v[p] + bias[p], 0.f);
    }

    bf16x8 o;
    #pragma unroll
    for (int p = 0; p < 8; ++p)
        o[p] = (__bf16)fmaxf(acc[p] * 0.125f, 0.f);
    *(bf16x8*)(E1b + (size_t)(i0 + il) * JDIM + c0) = o;
}

// ---------------------------------------------------------------------------
// Kernel 3 (MFMA): E2 = relu(concat(Hb,E1b) @ Wg + bg);  out = E2 @ Wf + bf
// [R3-proven version] Block 128 rows; wave = 2 m-tiles x 8 n-tiles.
// ---------------------------------------------------------------------------
__global__ __launch_bounds__(256) void k_final_mfma(
    const __bf16* __restrict__ Hb, const __bf16* __restrict__ E1b,
    const __bf16* __restrict__ Wt, const float* __restrict__ bg,
    const float* __restrict__ Wf, const float* __restrict__ bf,
    float* __restrict__ out)
{
    __shared__ __bf16 E2s[128][136];

    const int tid  = threadIdx.x;
    const int row0 = blockIdx.x * 128;
    const int wave = tid >> 6, lane = tid & 63;
    const int lm = lane & 15, lq = lane >> 4;

    bf16x8 aall[2][8];
    #pragma unroll
    for (int t = 0; t < 2; ++t) {
        int grow = row0 + wave * 32 + t * 16 + lm;
        if (grow >= L_NODES) grow = L_NODES - 1;
        const __bf16* hp = Hb  + (size_t)grow * JDIM + lq * 8;
        const __bf16* ep = E1b + (size_t)grow * JDIM + lq * 8;
        #pragma unroll
        for (int kc = 0; kc < 4; ++kc) {
            aall[t][kc]     = *(const bf16x8*)(hp + kc * 32);
            aall[t][kc + 4] = *(const bf16x8*)(ep + kc * 32);
        }
    }

    const __bf16* bptr[8];
    #pragma unroll
    for (int nt = 0; nt < 8; ++nt)
        bptr[nt] = Wt + (size_t)(nt * 16 + lm) * 256 + lq * 8;

    floatx4 acc[2][8] = {};
    bf16x8 bc[8], bn[8];
    #pragma unroll
    for (int nt = 0; nt < 8; ++nt) bc[nt] = *(const bf16x8*)bptr[nt];

    #pragma unroll
    for (int ks = 0; ks < 8; ++ks) {
        if (ks < 7)
            #pragma unroll
            for (int nt = 0; nt < 8; ++nt)
                bn[nt] = *(const bf16x8*)(bptr[nt] + (ks + 1) * 32);
        #pragma unroll
        for (int t = 0; t < 2; ++t)
            #pragma unroll
            for (int nt = 0; nt < 8; ++nt)
                acc[t][nt] = __builtin_amdgcn_mfma_f32_16x16x32_bf16(
                    aall[t][ks], bc[nt], acc[t][nt], 0, 0, 0);
        #pragma unroll
        for (int nt = 0; nt < 8; ++nt) bc[nt] = bn[nt];
    }

    #pragma unroll
    for (int nt = 0; nt < 8; ++nt) {
        int col = nt * 16 + lm;
        float bias = bg[col];
        #pragma unroll
        for (int t = 0; t < 2; ++t)
            #pragma unroll
            for (int p = 0; p < 4; ++p)
                E2s[wave * 32 + t * 16 + lq * 4 + p][col] =
                    (__bf16)fmaxf(acc[t][nt][p] + bias, 0.f);
    }
    __syncthreads();

    {
        int row = tid >> 1, o = tid & 1;
        int grow = row0 + row;
        if (grow < L_NODES) {
            float a = bf[o];
            #pragma unroll
            for (int j = 0; j < 16; ++j) {
                bf16x8 v = *(bf16x8*)&E2s[row][j * 8];
                #pragma unroll
                for (int c = 0; c < 8; ++c)
                    a = fmaf((float)v[c], Wf[(j * 8 + c) * 2 + o], a);
            }
            out[(size_t)grow * 2 + o] = a;
        }
    }
}

// ---------------------------------------------------------------------------
extern "C" void kernel_launch(void* const* d_in, const int* in_sizes, int n_in,
                              void* d_out, int out_size, void* d_ws, size_t ws_size,
                              hipStream_t stream) {
    const float* X    = (const float*)d_in[0];
    const float* W_h1 = (const float*)d_in[1];
    const float* b_h1 = (const float*)d_in[2];
    const float* W_g1 = (const float*)d_in[3];
    const float* b_g1 = (const float*)d_in[4];
    const float* W_f  = (const float*)d_in[5];
    const float* b_f  = (const float*)d_in[6];
    const int*   idx0 = (const int*)d_in[7];
    const int*   idx1 = (const int*)d_in[8];
    float* out = (float*)d_out;

    // d_ws: exactly 4 x 25.6e6 B = 102.4e6 B (same footprint R1 proved fits)
    __bf16* Hb  = (__bf16*)d_ws;                          // 25.6 MB
    __bf16* E1b = Hb  + (size_t)L_NODES * JDIM;           // 25.6 MB
    __bf16* U   = E1b + (size_t)L_NODES * JDIM;           // 25.6 MB (dead after gather)
    __bf16* V   = U   + (size_t)L_NODES * JDIM;           // 25.6 MB

    // transposed weights live in d_out (scratch until k_final rewrites all of
    // out) and, for k_final's copy, in U's space after U dies (k_prep2).
    __bf16* WtH  = (__bf16*)d_out;        // 64 KB, dead after k_h1
    __bf16* WtGu = WtH + 32768;           // 64 KB, dead after k_uv
    __bf16* WtGf = U;                     // written by k_prep2 after k_gather

    k_prep<<<128, 256, 0, stream>>>(W_h1, W_g1, WtH, WtGu);
    k_h1_mfma<<<(L_NODES + 127) / 128, 256, 0, stream>>>(X, WtH, b_h1, Hb);
    k_uv<<<(L_NODES + 63) / 64, 256, 0, stream>>>(Hb, WtGu, U, V);
    k_gather<<<L_NODES / 16, 256, 0, stream>>>(U, V, b_g1, idx0, idx1, E1b);
    k_prep2<<<128, 256, 0, stream>>>(W_g1, WtGf);
    k_final_mfma<<<(L_NODES + 127) / 128, 256, 0, stream>>>(Hb, E1b, WtGf, b_g1, W_f, b_f, out);
}

// Round 6
// 310.713 us; speedup vs baseline: 1.5821x; 1.0303x over previous
//
#include <hip/hip_runtime.h>

#define L_NODES 100000
#define NFEAT   256
#define JDIM    128

typedef __bf16 bf16x8 __attribute__((ext_vector_type(8)));
typedef __bf16 bf16x4 __attribute__((ext_vector_type(4)));
typedef float  floatx4 __attribute__((ext_vector_type(4)));

// ---------------------------------------------------------------------------
// Prep: WtH[n][k]=bf16(W_h1[k][n]), WtGu[n][k]=bf16(W_g1[k][n]) -> into d_out
// ---------------------------------------------------------------------------
__global__ __launch_bounds__(256) void k_prep(
    const float* __restrict__ Wh, const float* __restrict__ Wg,
    __bf16* __restrict__ WtH, __bf16* __restrict__ WtGu)
{
    int i = blockIdx.x * 256 + threadIdx.x;   // 32768
    int n = i >> 8, k = i & 255;
    WtH[i]  = (__bf16)Wh[k * JDIM + n];
    WtGu[i] = (__bf16)Wg[k * JDIM + n];
}

// Prep2b (after k_gather, V dead): WtGb[n][k] = bf16(Wg[128+k][n]), 32 KB
__global__ __launch_bounds__(256) void k_prep2b(
    const float* __restrict__ Wg, __bf16* __restrict__ WtGb)
{
    int i = blockIdx.x * 256 + threadIdx.x;   // 16384
    int n = i >> 7, k = i & 127;
    WtGb[i] = (__bf16)Wg[(128 + k) * JDIM + n];
}

// ---------------------------------------------------------------------------
// Kernel 1 (MFMA): Hb = bf16(relu(X @ W_h1 + b))   [R3-proven]
// ---------------------------------------------------------------------------
__global__ __launch_bounds__(256) void k_h1_mfma(
    const float* __restrict__ X, const __bf16* __restrict__ WtH,
    const float* __restrict__ b, __bf16* __restrict__ Hb)
{
    __shared__ __bf16 As[128][136];

    const int tid  = threadIdx.x;
    const int row0 = blockIdx.x * 128;
    const int wave = tid >> 6, lane = tid & 63;
    const int mh = wave >> 1, wc = wave & 1;
    const int lm = lane & 15, lq = lane >> 4;

    const __bf16* bptr[4];
    #pragma unroll
    for (int nt = 0; nt < 4; ++nt)
        bptr[nt] = WtH + (size_t)(wc * 64 + nt * 16 + lm) * 256 + lq * 8;

    floatx4 acc[4][4] = {};
    bf16x8 bc[4], bn[4];
    #pragma unroll
    for (int nt = 0; nt < 4; ++nt) bc[nt] = *(const bf16x8*)bptr[nt];

    for (int half = 0; half < 2; ++half) {
        #pragma unroll
        for (int it = 0; it < 16; ++it) {
            int f4  = it * 256 + tid;
            int row = f4 >> 5;
            int c4  = f4 & 31;
            int grow = row0 + row; if (grow >= L_NODES) grow = L_NODES - 1;
            float4 v = *(const float4*)(X + (size_t)grow * NFEAT + half * 128 + c4 * 4);
            bf16x4 o; o[0]=(__bf16)v.x; o[1]=(__bf16)v.y; o[2]=(__bf16)v.z; o[3]=(__bf16)v.w;
            *(bf16x4*)&As[row][c4 * 4] = o;
        }
        __syncthreads();
        #pragma unroll
        for (int ksl = 0; ksl < 4; ++ksl) {
            int ks = half * 4 + ksl;
            if (ks < 7)
                #pragma unroll
                for (int nt = 0; nt < 4; ++nt)
                    bn[nt] = *(const bf16x8*)(bptr[nt] + (ks + 1) * 32);
            bf16x8 af[4];
            #pragma unroll
            for (int t = 0; t < 4; ++t)
                af[t] = *(const bf16x8*)&As[mh * 64 + t * 16 + lm][ksl * 32 + lq * 8];
            #pragma unroll
            for (int t = 0; t < 4; ++t)
                #pragma unroll
                for (int nt = 0; nt < 4; ++nt)
                    acc[t][nt] = __builtin_amdgcn_mfma_f32_16x16x32_bf16(
                        af[t], bc[nt], acc[t][nt], 0, 0, 0);
            #pragma unroll
            for (int nt = 0; nt < 4; ++nt) bc[nt] = bn[nt];
        }
        __syncthreads();
    }

    #pragma unroll
    for (int nt = 0; nt < 4; ++nt) {
        int col = wc * 64 + nt * 16 + lm;
        float bias = b[col];
        #pragma unroll
        for (int t = 0; t < 4; ++t)
            #pragma unroll
            for (int p = 0; p < 4; ++p)
                As[mh * 64 + t * 16 + lq * 4 + p][col] =
                    (__bf16)fmaxf(acc[t][nt][p] + bias, 0.f);
    }
    __syncthreads();
    {
        int row = tid >> 1, hf = tid & 1;
        int grow = row0 + row;
        if (grow < L_NODES) {
            #pragma unroll
            for (int j = 0; j < 8; ++j) {
                bf16x8 v = *(bf16x8*)&As[row][hf * 64 + j * 8];
                *(bf16x8*)(Hb + (size_t)grow * JDIM + hf * 64 + j * 8) = v;
            }
        }
    }
}

// ---------------------------------------------------------------------------
// Kernel 2a (MFMA): U = Hb @ Wg[0:128,:], V = Hb @ Wg[128:256,:]  [R5-proven]
// ---------------------------------------------------------------------------
__global__ __launch_bounds__(256) void k_uv(
    const __bf16* __restrict__ Hb, const __bf16* __restrict__ WtGu,
    __bf16* __restrict__ U, __bf16* __restrict__ V)
{
    __shared__ __bf16 Os[64][264];

    const int tid  = threadIdx.x;
    const int row0 = blockIdx.x * 64;
    const int wave = tid >> 6, lane = tid & 63;
    const int wm = wave >> 1, wn = wave & 1;
    const int lm = lane & 15, lq = lane >> 4;

    bf16x8 aall[2][4];
    #pragma unroll
    for (int t = 0; t < 2; ++t) {
        int grow = row0 + wm * 32 + t * 16 + lm;
        if (grow >= L_NODES) grow = L_NODES - 1;
        const __bf16* hp = Hb + (size_t)grow * JDIM + lq * 8;
        #pragma unroll
        for (int ks = 0; ks < 4; ++ks)
            aall[t][ks] = *(const bf16x8*)(hp + ks * 32);
    }

    const __bf16* bbase = WtGu + (size_t)lm * 256 + wn * 128 + lq * 8;
    floatx4 acc[2][8] = {};
    #pragma unroll
    for (int ks = 0; ks < 4; ++ks) {
        bf16x8 bc[8];
        #pragma unroll
        for (int nt = 0; nt < 8; ++nt)
            bc[nt] = *(const bf16x8*)(bbase + (size_t)nt * 16 * 256 + ks * 32);
        #pragma unroll
        for (int t = 0; t < 2; ++t)
            #pragma unroll
            for (int nt = 0; nt < 8; ++nt)
                acc[t][nt] = __builtin_amdgcn_mfma_f32_16x16x32_bf16(
                    aall[t][ks], bc[nt], acc[t][nt], 0, 0, 0);
    }

    #pragma unroll
    for (int nt = 0; nt < 8; ++nt) {
        int col = wn * 128 + nt * 16 + lm;
        #pragma unroll
        for (int t = 0; t < 2; ++t)
            #pragma unroll
            for (int p = 0; p < 4; ++p)
                Os[wm * 32 + t * 16 + lq * 4 + p][col] = (__bf16)acc[t][nt][p];
    }
    __syncthreads();
    #pragma unroll
    for (int it = 0; it < 8; ++it) {
        int fid = it * 256 + tid;
        int row = fid >> 5, c8 = fid & 31;
        int grow = row0 + row;
        if (grow < L_NODES) {
            int col = c8 * 8;
            bf16x8 v = *(bf16x8*)&Os[row][col];
            if (col < 128)
                *(bf16x8*)(U + (size_t)grow * JDIM + col) = v;
            else
                *(bf16x8*)(V + (size_t)grow * JDIM + (col - 128)) = v;
        }
    }
}

// ---------------------------------------------------------------------------
// Kernel 2b (gather-add): E1b[i] = bf16(relu(mean_s relu(U[idx0]+V[idx1]+b)))
// 32 nodes/block, 2 nodes/thread -> 32 independent gather loads in flight.
// ---------------------------------------------------------------------------
__global__ __launch_bounds__(256) void k_gather(
    const __bf16* __restrict__ U, const __bf16* __restrict__ V,
    const float* __restrict__ b,
    const int* __restrict__ idx0, const int* __restrict__ idx1,
    __bf16* __restrict__ E1b)
{
    __shared__ int s0[8][32], s1[8][32];

    const int tid = threadIdx.x;
    const int i0  = blockIdx.x * 32;

    {
        int s = tid >> 5, il = tid & 31;
        s0[s][il] = idx0[(size_t)s * L_NODES + i0 + il];
        s1[s][il] = idx1[(size_t)s * L_NODES + i0 + il];
    }
    __syncthreads();

    const int il = tid >> 4;            // 0..15 (handles nodes il and il+16)
    const int c0 = (tid & 15) * 8;

    float bias[8];
    *(float4*)&bias[0] = *(const float4*)(b + c0);
    *(float4*)&bias[4] = *(const float4*)(b + c0 + 4);

    float acca[8] = {}, accb[8] = {};
    #pragma unroll
    for (int s = 0; s < 8; ++s) {
        int a0 = s0[s][il],      a1 = s1[s][il];
        int b0 = s0[s][il + 16], b1 = s1[s][il + 16];
        bf16x8 ua = *(const bf16x8*)(U + (size_t)a0 * JDIM + c0);
        bf16x8 va = *(const bf16x8*)(V + (size_t)a1 * JDIM + c0);
        bf16x8 ub = *(const bf16x8*)(U + (size_t)b0 * JDIM + c0);
        bf16x8 vb = *(const bf16x8*)(V + (size_t)b1 * JDIM + c0);
        #pragma unroll
        for (int p = 0; p < 8; ++p) {
            acca[p] += fmaxf((float)ua[p] + (float)va[p] + bias[p], 0.f);
            accb[p] += fmaxf((float)ub[p] + (float)vb[p] + bias[p], 0.f);
        }
    }

    bf16x8 oa, ob;
    #pragma unroll
    for (int p = 0; p < 8; ++p) {
        oa[p] = (__bf16)fmaxf(acca[p] * 0.125f, 0.f);
        ob[p] = (__bf16)fmaxf(accb[p] * 0.125f, 0.f);
    }
    *(bf16x8*)(E1b + (size_t)(i0 + il) * JDIM + c0) = oa;
    *(bf16x8*)(E1b + (size_t)(i0 + il + 16) * JDIM + c0) = ob;
}

// ---------------------------------------------------------------------------
// Kernel 3 (MFMA, K=128): E2 = relu(U + E1b @ Wg[128:,:] + bg); out = E2@Wf+bf
// Uses the identity concat(H,E1)@Wg = U + E1@Wg_bot (U precomputed).
// U staged coalesced into LDS; epilogue does in-place read-add-relu-write
// (each (row,col) owned by exactly one thread). Then fused J->2 head.
// ---------------------------------------------------------------------------
__global__ __launch_bounds__(256) void k_final2(
    const __bf16* __restrict__ U, const __bf16* __restrict__ E1b,
    const __bf16* __restrict__ WtGb, const float* __restrict__ bg,
    const float* __restrict__ Wf, const float* __restrict__ bf,
    float* __restrict__ out)
{
    __shared__ __bf16 E2s[128][136];

    const int tid  = threadIdx.x;
    const int row0 = blockIdx.x * 128;
    const int wave = tid >> 6, lane = tid & 63;
    const int lm = lane & 15, lq = lane >> 4;

    // stage U tile (128x128 bf16) coalesced into LDS
    #pragma unroll
    for (int it = 0; it < 8; ++it) {
        int fid = it * 256 + tid;
        int row = fid >> 4, fr = fid & 15;
        int g = row0 + row; if (g >= L_NODES) g = L_NODES - 1;
        *(bf16x8*)&E2s[row][fr * 8] = *(const bf16x8*)(U + (size_t)g * JDIM + fr * 8);
    }

    // A-frags: E1b rows, K=128
    bf16x8 aall[2][4];
    #pragma unroll
    for (int t = 0; t < 2; ++t) {
        int grow = row0 + wave * 32 + t * 16 + lm;
        if (grow >= L_NODES) grow = L_NODES - 1;
        const __bf16* ep = E1b + (size_t)grow * JDIM + lq * 8;
        #pragma unroll
        for (int kc = 0; kc < 4; ++kc)
            aall[t][kc] = *(const bf16x8*)(ep + kc * 32);
    }

    const __bf16* bbase = WtGb + (size_t)lm * 128 + lq * 8;
    floatx4 acc[2][8] = {};
    #pragma unroll
    for (int ks = 0; ks < 4; ++ks) {
        bf16x8 bc[8];
        #pragma unroll
        for (int nt = 0; nt < 8; ++nt)
            bc[nt] = *(const bf16x8*)(bbase + (size_t)nt * 16 * 128 + ks * 32);
        #pragma unroll
        for (int t = 0; t < 2; ++t)
            #pragma unroll
            for (int nt = 0; nt < 8; ++nt)
                acc[t][nt] = __builtin_amdgcn_mfma_f32_16x16x32_bf16(
                    aall[t][ks], bc[nt], acc[t][nt], 0, 0, 0);
    }
    __syncthreads();   // U staging visible to all

    // epilogue: E2s[r][c] = relu(U + acc + bias), in place
    #pragma unroll
    for (int nt = 0; nt < 8; ++nt) {
        int col = nt * 16 + lm;
        float bias = bg[col];
        #pragma unroll
        for (int t = 0; t < 2; ++t)
            #pragma unroll
            for (int p = 0; p < 4; ++p) {
                int r = wave * 32 + t * 16 + lq * 4 + p;
                float u = (float)E2s[r][col];
                E2s[r][col] = (__bf16)fmaxf(u + acc[t][nt][p] + bias, 0.f);
            }
    }
    __syncthreads();

    // head: out[row][o] = E2[row] . Wf[:,o] + bf[o]
    {
        int row = tid >> 1, o = tid & 1;
        int grow = row0 + row;
        if (grow < L_NODES) {
            float a = bf[o];
            #pragma unroll
            for (int j = 0; j < 16; ++j) {
                bf16x8 v = *(bf16x8*)&E2s[row][j * 8];
                #pragma unroll
                for (int c = 0; c < 8; ++c)
                    a = fmaf((float)v[c], Wf[(j * 8 + c) * 2 + o], a);
            }
            out[(size_t)grow * 2 + o] = a;
        }
    }
}

// ---------------------------------------------------------------------------
extern "C" void kernel_launch(void* const* d_in, const int* in_sizes, int n_in,
                              void* d_out, int out_size, void* d_ws, size_t ws_size,
                              hipStream_t stream) {
    const float* X    = (const float*)d_in[0];
    const float* W_h1 = (const float*)d_in[1];
    const float* b_h1 = (const float*)d_in[2];
    const float* W_g1 = (const float*)d_in[3];
    const float* b_g1 = (const float*)d_in[4];
    const float* W_f  = (const float*)d_in[5];
    const float* b_f  = (const float*)d_in[6];
    const int*   idx0 = (const int*)d_in[7];
    const int*   idx1 = (const int*)d_in[8];
    float* out = (float*)d_out;

    __bf16* Hb  = (__bf16*)d_ws;                          // 25.6 MB (dead after uv)
    __bf16* E1b = Hb  + (size_t)L_NODES * JDIM;           // 25.6 MB
    __bf16* U   = E1b + (size_t)L_NODES * JDIM;           // 25.6 MB (live to end)
    __bf16* V   = U   + (size_t)L_NODES * JDIM;           // 25.6 MB (dead after gather)

    __bf16* WtH  = (__bf16*)d_out;        // 64 KB scratch in d_out, dead after k_h1
    __bf16* WtGu = WtH + 32768;           // 64 KB, dead after k_uv
    __bf16* WtGb = V;                     // 32 KB, written after gather (V dead)

    k_prep<<<128, 256, 0, stream>>>(W_h1, W_g1, WtH, WtGu);
    k_h1_mfma<<<(L_NODES + 127) / 128, 256, 0, stream>>>(X, WtH, b_h1, Hb);
    k_uv<<<(L_NODES + 63) / 64, 256, 0, stream>>>(Hb, WtGu, U, V);
    k_gather<<<L_NODES / 32, 256, 0, stream>>>(U, V, b_g1, idx0, idx1, E1b);
    k_prep2b<<<64, 256, 0, stream>>>(W_g1, WtGb);
    k_final2<<<(L_NODES + 127) / 128, 256, 0, stream>>>(U, E1b, WtGb, b_g1, W_f, b_f, out);
}